// Round 8
// baseline (116.124 us; speedup 1.0000x reference)
//
#include <hip/hip_runtime.h>
#include <hip/hip_bf16.h>

// JPEG 8x8 block DCT + quantization.
// image: [16,1,1024,1024] fp32; quality_factor: [16] fp32
// out:   [16,64,128,128] fp32, channel = k*8+l, out = (C @ (blk-128) @ C^T) / (factor*Q)
//
// R11 == R9 resubmitted (second consecutive infra failure on this variant; no
// measurement yet). Theory vs R7 (measured: R3/R4/R7 all ~111.3-112.0 harness;
// kernel ~28us by subtraction vs 21.5us BW floor. Model: full-grid residency +
// upfront loads => globally serialized phases: 10.5us pure-read + ~5us compute
// (HBM idle) + 10.5us pure-write. Intra-phase fixes (R4 burst, R7 barrier-free)
// were off the critical path — only cross-phase overlap helps):
//  - TWO blocks per thread (vertically adjacent h-pairs A,B). Issue A loads then
//    B loads (32KiB MLP/wave); compute+store A while B's loads are in flight
//    (first A use waits vmcnt(16)); then compute+store B. A-stores interleave
//    with B-reads globally -> read/write streams merge.
//  - Grid 512 WGs (2/CU), __launch_bounds__(256,2): VGPR peak ~160 (two 64-reg
//    load sets), 2 waves/SIMD.
//  - Register enabler: fold the -128 shift into k=0 (sum(DCT[k,:])==0 for k!=0;
//    k=0: subtract 128*8*0.35355339 = 362.038672 from tk[m]). Removes r[8][8].
//    Error <= 1e-5, tolerance 0.5.
//  - Wave-private barrier-free LDS transpose epilogue unchanged (verified R7).

#define BS 8
#define HPIX 1024
#define WPIX 1024
#define HB (HPIX / BS)   // 128
#define WB (WPIX / BS)   // 128
#define BATCH 16

// Orthonormal DCT-II matrix C[k][n] = f_k * cos(pi*(2n+1)*k/16), fp32-rounded.
constexpr float DCT[8][8] = {
  { 0.35355339059327373f,  0.35355339059327373f,  0.35355339059327373f,  0.35355339059327373f,
    0.35355339059327373f,  0.35355339059327373f,  0.35355339059327373f,  0.35355339059327373f },
  { 0.49039264020161522f,  0.41573480615127262f,  0.27778511650980114f,  0.09754516100806413f,
   -0.09754516100806413f, -0.27778511650980114f, -0.41573480615127262f, -0.49039264020161522f },
  { 0.46193976625564337f,  0.19134171618254492f, -0.19134171618254492f, -0.46193976625564337f,
   -0.46193976625564337f, -0.19134171618254492f,  0.19134171618254492f,  0.46193976625564337f },
  { 0.41573480615127262f, -0.09754516100806413f, -0.49039264020161522f, -0.27778511650980114f,
    0.27778511650980114f,  0.49039264020161522f,  0.09754516100806413f, -0.41573480615127262f },
  { 0.35355339059327373f, -0.35355339059327373f, -0.35355339059327373f,  0.35355339059327373f,
    0.35355339059327373f, -0.35355339059327373f, -0.35355339059327373f,  0.35355339059327373f },
  { 0.27778511650980114f, -0.49039264020161522f,  0.09754516100806413f,  0.41573480615127262f,
   -0.41573480615127262f, -0.09754516100806413f,  0.49039264020161522f, -0.27778511650980114f },
  { 0.19134171618254492f, -0.46193976625564337f,  0.46193976625564337f, -0.19134171618254492f,
   -0.19134171618254492f,  0.46193976625564337f, -0.46193976625564337f,  0.19134171618254492f },
  { 0.09754516100806413f, -0.27778511650980114f,  0.41573480615127262f, -0.49039264020161522f,
    0.49039264020161522f, -0.41573480615127262f,  0.27778511650980114f, -0.09754516100806413f },
};

// 1 / (LUMINANCE_QUANTIZATION_TABLE / 100) = 100 / table entry
constexpr float INVQ[8][8] = {
  { 6.25f,              9.09090909090909f,  10.0f,              6.25f,
    4.16666666666667f,  2.5f,               1.96078431372549f,  1.63934426229508f },
  { 8.33333333333333f,  8.33333333333333f,  7.14285714285714f,  5.26315789473684f,
    3.84615384615385f,  1.72413793103448f,  1.66666666666667f,  1.81818181818182f },
  { 7.14285714285714f,  7.69230769230769f,  6.25f,              4.16666666666667f,
    2.5f,               1.75438596491228f,  1.44927536231884f,  1.78571428571429f },
  { 7.14285714285714f,  5.88235294117647f,  4.54545454545455f,  3.44827586206897f,
    1.96078431372549f,  1.14942528735632f,  1.25f,              1.61290322580645f },
  { 5.55555555555556f,  4.54545454545455f,  2.70270270270270f,  1.78571428571429f,
    1.47058823529412f,  0.91743119266055f,  0.970873786407767f, 1.29870129870130f },
  { 4.16666666666667f,  2.77777777777778f,  1.81818181818182f,  1.5625f,
    1.23456790123457f,  0.961538461538462f, 0.884955752212389f, 1.08695652173913f },
  { 2.04081632653061f,  1.5625f,            1.28205128205128f,  1.14942528735632f,
    0.970873786407767f, 0.826446280991736f, 0.833333333333333f, 0.990099009900990f },
  { 1.38888888888889f,  1.08695652173913f,  1.05263157894737f,  1.02040816326531f,
    0.892857142857143f, 1.0f,               0.970873786407767f, 1.01010101010101f },
};

// 128 * sum(DCT[0][:]) = 128 * 8 * 0.35355339059327373
#define K0_SHIFT 362.03867196751236f

// Process one 8x8 block held in (v0[n], v1[n]) = pixels [0..3],[4..7] of row n.
// Wave-private LDS transpose, no barriers (same-wave lgkmcnt ordering), ping-pong.
__device__ __forceinline__ void process_block(
    const float4 v0[8], const float4 v1[8],
    float rf, int lane, int row0, int chunk,
    float (&ldsw)[2][8][64],          // this wave's LDS region
    float* __restrict__ dstbase)      // out + obatch + h*WB + wbase
{
#pragma unroll
    for (int k = 0; k < 8; ++k) {
        const int buf = k & 1;

        float tk[8];
#pragma unroll
        for (int m = 0; m < 8; ++m)
            tk[m] = 0.0f;
#pragma unroll
        for (int n = 0; n < 8; ++n) {
            const float cf = DCT[k][n];   // constexpr -> immediate
            tk[0] = fmaf(cf, v0[n].x, tk[0]);
            tk[1] = fmaf(cf, v0[n].y, tk[1]);
            tk[2] = fmaf(cf, v0[n].z, tk[2]);
            tk[3] = fmaf(cf, v0[n].w, tk[3]);
            tk[4] = fmaf(cf, v1[n].x, tk[4]);
            tk[5] = fmaf(cf, v1[n].y, tk[5]);
            tk[6] = fmaf(cf, v1[n].z, tk[6]);
            tk[7] = fmaf(cf, v1[n].w, tk[7]);
        }
        if (k == 0) {
            // -128 pixel shift folded: only the DC row has nonzero DCT row-sum.
#pragma unroll
            for (int m = 0; m < 8; ++m)
                tk[m] -= K0_SHIFT;
        }

#pragma unroll
        for (int l = 0; l < 8; ++l) {
            float s = 0.0f;
#pragma unroll
            for (int m = 0; m < 8; ++m)
                s = fmaf(DCT[l][m], tk[m], s);
            ldsw[buf][l][lane] = s * rf * INVQ[k][l];
        }

#pragma unroll
        for (int it = 0; it < 2; ++it) {
            const int row = row0 + 4 * it;           // channel l within this k
            float4 v = *reinterpret_cast<const float4*>(&ldsw[buf][row][4 * chunk]);
            float* dst = dstbase + (size_t)(k * 8 + row) * (HB * WB) + 4 * chunk;
            *reinterpret_cast<float4*>(dst) = v;
        }
    }
}

// WG = 256 threads = 4 consecutive block-rows (h0..h0+3) x 128 block-cols, one batch.
// Wave wv (= t>>6): hsub = wv>>1, block-col range [64*(wv&1), +64).
// Thread handles blocks A (h0+hsub) and B (h0+2+hsub).
// Grid = 16 batches * 32 h-quads = 512 WGs (2 WGs/CU, all resident).
__global__ __launch_bounds__(256, 2) void jpeg_dct_q_kernel(
    const float* __restrict__ img,
    const float* __restrict__ qf,
    float* __restrict__ out)
{
    // Wave-private ping-pong staging: [wave][buf][l][w64]; 4*2*8*64*4B = 16 KB
    __shared__ float lds[4][2][8][64];

    const int t = threadIdx.x;
    const int lane = t & 63;
    const int wv = t >> 6;
    const int g = blockIdx.x;
    const int b = g >> 5;                 // batch
    const int h0 = (g & 31) << 2;         // first of 4 block-rows
    const int hsub = wv >> 1;             // 0/1 within a pair
    const int wbase = (wv & 1) << 6;      // 0 or 64
    const int w = wbase + lane;           // block col
    const int hA = h0 + hsub;
    const int hB = h0 + 2 + hsub;

    const float* baseA = img + ((size_t)b << 20) + (size_t)(hA * BS) * WPIX + (size_t)(w * BS);
    const float* baseB = img + ((size_t)b << 20) + (size_t)(hB * BS) * WPIX + (size_t)(w * BS);

    // ---- Load bursts: A then B, all 32 dwordx4 in flight (32 KiB/wave) ----
    float4 a0[8], a1[8], b0[8], b1[8];
#pragma unroll
    for (int n = 0; n < 8; ++n) {
        const float4* p = reinterpret_cast<const float4*>(baseA + n * WPIX);
        a0[n] = p[0];
        a1[n] = p[1];
    }
#pragma unroll
    for (int n = 0; n < 8; ++n) {
        const float4* p = reinterpret_cast<const float4*>(baseB + n * WPIX);
        b0[n] = p[0];
        b1[n] = p[1];
    }
    // Pin both bursts before any compute (keep B's loads from sinking below A's
    // compute under register pressure). No instruction emitted.
    asm volatile("" ::: "memory");

    // Quantization scale: factor = QF<50 ? 5000/QF : 200-2*QF
    const float q = qf[b];
    const float factor = (q < 50.0f) ? (5000.0f / q) : (200.0f - 2.0f * q);
    const float rf = 1.0f / factor;

    // Flush mapping, within-wave: lane -> (row0 = lane>>4, chunk = lane&15).
    const int row0 = lane >> 4;           // 0..3
    const int chunk = lane & 15;          // w-group of 4 within this wave's 64 cols
    const size_t obatch = (size_t)b << 20;

    float* dstA = out + obatch + (size_t)hA * WB + wbase;
    float* dstB = out + obatch + (size_t)hB * WB + wbase;

    // A: first use waits vmcnt(16) — B's 16 loads stay in flight under A's
    // ~2500-cycle compute+store. Then B with data already resident.
    process_block(a0, a1, rf, lane, row0, chunk, lds[wv], dstA);
    process_block(b0, b1, rf, lane, row0, chunk, lds[wv], dstB);
}

extern "C" void kernel_launch(void* const* d_in, const int* in_sizes, int n_in,
                              void* d_out, int out_size, void* d_ws, size_t ws_size,
                              hipStream_t stream) {
    const float* img = (const float*)d_in[0];
    const float* qf  = (const float*)d_in[1];
    float* out = (float*)d_out;

    const int grid = BATCH * (HB / 4);   // 512 WGs: one per (batch, 4-row quad)
    const int block = 256;

    jpeg_dct_q_kernel<<<grid, block, 0, stream>>>(img, qf, out);
}

// Round 13
// 111.805 us; speedup vs baseline: 1.0386x; 1.0386x over previous
//
#include <hip/hip_runtime.h>
#include <hip/hip_bf16.h>

// JPEG 8x8 block DCT + quantization.
// image: [16,1,1024,1024] fp32; quality_factor: [16] fp32
// out:   [16,64,128,128] fp32, channel = k*8+l, out = (C @ (blk-128) @ C^T) / (factor*Q)
//
// R16 == R12 resubmitted (fourth consecutive infra failure on this variant).
// Theory vs R7 (measured: R7=111.25us; R9 two-block pipeline REGRESSED to
// 116.12 — halving occupancy removed the wave-interleave that was already
// overlapping compute with the read stream. Model: at 16 waves/CU the memory
// phases overlap via TLP; the residual ~7us over the 21.3us floor is partly the
// ~4us per-SIMD VALU bulge during which SIMDs stop issuing memory):
//  - REVERT to R7 structure: grid 1024, __launch_bounds__(256,4), 16 waves/CU,
//    wave-private barrier-free LDS transpose epilogue (verified).
//  - Even/odd butterfly DCT in BOTH stages (DCT[k][n] = +/-DCT[k][7-n]):
//    stage1: p/q = row sums/diffs once (64 adds), then 4-term FMAs (32/k);
//    stage2: u/v = tk sums/diffs (8/k), then 4-term FMAs (32/k).
//    VALU ~768 instr/thread vs ~1150 -> per-SIMD compute ~3.9 -> ~2.6us.
//  - K0_SHIFT fold kept (verified correct in R9): load raw pixels; only k=0 has
//    nonzero DCT row-sum, subtract 128*8*0.35355339 = 362.038672 there.
//  - Memory pattern / LDS mapping / store addresses bit-identical to R7.

#define BS 8
#define HPIX 1024
#define WPIX 1024
#define HB (HPIX / BS)   // 128
#define WB (WPIX / BS)   // 128
#define BATCH 16

// Orthonormal DCT-II matrix C[k][n] = f_k * cos(pi*(2n+1)*k/16), fp32-rounded.
constexpr float DCT[8][8] = {
  { 0.35355339059327373f,  0.35355339059327373f,  0.35355339059327373f,  0.35355339059327373f,
    0.35355339059327373f,  0.35355339059327373f,  0.35355339059327373f,  0.35355339059327373f },
  { 0.49039264020161522f,  0.41573480615127262f,  0.27778511650980114f,  0.09754516100806413f,
   -0.09754516100806413f, -0.27778511650980114f, -0.41573480615127262f, -0.49039264020161522f },
  { 0.46193976625564337f,  0.19134171618254492f, -0.19134171618254492f, -0.46193976625564337f,
   -0.46193976625564337f, -0.19134171618254492f,  0.19134171618254492f,  0.46193976625564337f },
  { 0.41573480615127262f, -0.09754516100806413f, -0.49039264020161522f, -0.27778511650980114f,
    0.27778511650980114f,  0.49039264020161522f,  0.09754516100806413f, -0.41573480615127262f },
  { 0.35355339059327373f, -0.35355339059327373f, -0.35355339059327373f,  0.35355339059327373f,
    0.35355339059327373f, -0.35355339059327373f, -0.35355339059327373f,  0.35355339059327373f },
  { 0.27778511650980114f, -0.49039264020161522f,  0.09754516100806413f,  0.41573480615127262f,
   -0.41573480615127262f, -0.09754516100806413f,  0.49039264020161522f, -0.27778511650980114f },
  { 0.19134171618254492f, -0.46193976625564337f,  0.46193976625564337f, -0.19134171618254492f,
   -0.19134171618254492f,  0.46193976625564337f, -0.46193976625564337f,  0.19134171618254492f },
  { 0.09754516100806413f, -0.27778511650980114f,  0.41573480615127262f, -0.49039264020161522f,
    0.49039264020161522f, -0.41573480615127262f,  0.27778511650980114f, -0.09754516100806413f },
};

// 1 / (LUMINANCE_QUANTIZATION_TABLE / 100) = 100 / table entry
constexpr float INVQ[8][8] = {
  { 6.25f,              9.09090909090909f,  10.0f,              6.25f,
    4.16666666666667f,  2.5f,               1.96078431372549f,  1.63934426229508f },
  { 8.33333333333333f,  8.33333333333333f,  7.14285714285714f,  5.26315789473684f,
    3.84615384615385f,  1.72413793103448f,  1.66666666666667f,  1.81818181818182f },
  { 7.14285714285714f,  7.69230769230769f,  6.25f,              4.16666666666667f,
    2.5f,               1.75438596491228f,  1.44927536231884f,  1.78571428571429f },
  { 7.14285714285714f,  5.88235294117647f,  4.54545454545455f,  3.44827586206897f,
    1.96078431372549f,  1.14942528735632f,  1.25f,              1.61290322580645f },
  { 5.55555555555556f,  4.54545454545455f,  2.70270270270270f,  1.78571428571429f,
    1.47058823529412f,  0.91743119266055f,  0.970873786407767f, 1.29870129870130f },
  { 4.16666666666667f,  2.77777777777778f,  1.81818181818182f,  1.5625f,
    1.23456790123457f,  0.961538461538462f, 0.884955752212389f, 1.08695652173913f },
  { 2.04081632653061f,  1.5625f,            1.28205128205128f,  1.14942528735632f,
    0.970873786407767f, 0.826446280991736f, 0.833333333333333f, 0.990099009900990f },
  { 1.38888888888889f,  1.08695652173913f,  1.05263157894737f,  1.02040816326531f,
    0.892857142857143f, 1.0f,               0.970873786407767f, 1.01010101010101f },
};

// 128 * sum(DCT[0][:]) = 128 * 8 * 0.35355339059327373
#define K0_SHIFT 362.03867196751236f

__device__ __forceinline__ float4 f4add(float4 a, float4 b) {
    return make_float4(a.x + b.x, a.y + b.y, a.z + b.z, a.w + b.w);
}
__device__ __forceinline__ float4 f4sub(float4 a, float4 b) {
    return make_float4(a.x - b.x, a.y - b.y, a.z - b.z, a.w - b.w);
}

// WG = 256 threads = 2 consecutive block-rows (h0, h0+1) x 128 block-cols, one batch.
// Wave wv (= t>>6): hsub = wv>>1, block-col range [64*(wv&1), 64*(wv&1)+64).
// Grid = 16 batches * 64 h-pairs = 1024 WGs (exactly 4 WGs/CU, all resident).
__global__ __launch_bounds__(256, 4) void jpeg_dct_q_kernel(
    const float* __restrict__ img,
    const float* __restrict__ qf,
    float* __restrict__ out)
{
    // Wave-private ping-pong staging: [wave][buf][l][w64]; 4*2*8*64*4B = 16 KB
    __shared__ float lds[4][2][8][64];

    const int t = threadIdx.x;
    const int lane = t & 63;
    const int wv = t >> 6;
    const int g = blockIdx.x;
    const int b = g >> 6;                 // batch
    const int h0 = (g & 63) << 1;         // first block-row of the pair
    const int hsub = wv >> 1;             // 0/1 within the pair
    const int wbase = (wv & 1) << 6;      // 0 or 64
    const int w = wbase + lane;           // block col (same global map as R3/R7)
    const int h = h0 + hsub;

    const float* rowbase = img + ((size_t)b << 20) + (size_t)(h * BS) * WPIX + (size_t)(w * BS);

    // ---- Load burst: all 16 global_load_dwordx4 issued back-to-back ----
    // Raw pixels (no -128: folded into k=0 via K0_SHIFT, verified in R9).
    float4 va[8], vb[8];
#pragma unroll
    for (int n = 0; n < 8; ++n) {
        const float4* p = reinterpret_cast<const float4*>(rowbase + n * WPIX);
        va[n] = p[0];
        vb[n] = p[1];
    }

    // ---- Stage-1 butterfly over rows n: DCT[k][7-n] = +DCT[k][n] (even k),
    // -DCT[k][n] (odd k). p = row sums, q = row diffs; va/vb die here.
    float4 p0[4], p1[4], q0[4], q1[4];
#pragma unroll
    for (int n = 0; n < 4; ++n) {
        p0[n] = f4add(va[n], va[7 - n]);
        q0[n] = f4sub(va[n], va[7 - n]);
        p1[n] = f4add(vb[n], vb[7 - n]);
        q1[n] = f4sub(vb[n], vb[7 - n]);
    }

    // Quantization scale: factor = QF<50 ? 5000/QF : 200-2*QF
    const float q = qf[b];
    const float factor = (q < 50.0f) ? (5000.0f / q) : (200.0f - 2.0f * q);
    const float rf = 1.0f / factor;

    // Flush mapping, within-wave: lane -> (row0 = lane>>4, chunk = lane&15).
    const int row0 = lane >> 4;           // 0..3
    const int chunk = lane & 15;          // w-group of 4 within this wave's 64 cols
    const size_t obatch = (size_t)b << 20;

    // Per DCT row k: 4-term stage-1 FMAs, stage-2 butterfly + 4-term FMAs,
    // -> wave-private LDS -> float4 stores. No __syncthreads anywhere
    // (same-wave lgkmcnt ordering, verified R7). Ping-pong WAR distance 2.
#pragma unroll
    for (int k = 0; k < 8; ++k) {
        const int buf = k & 1;
        const bool even = (k & 1) == 0;

        float tk[8];
#pragma unroll
        for (int m = 0; m < 8; ++m)
            tk[m] = 0.0f;
#pragma unroll
        for (int n = 0; n < 4; ++n) {
            const float cf = DCT[k][n];   // constexpr -> immediate
            const float4 s0 = even ? p0[n] : q0[n];
            const float4 s1 = even ? p1[n] : q1[n];
            tk[0] = fmaf(cf, s0.x, tk[0]);
            tk[1] = fmaf(cf, s0.y, tk[1]);
            tk[2] = fmaf(cf, s0.z, tk[2]);
            tk[3] = fmaf(cf, s0.w, tk[3]);
            tk[4] = fmaf(cf, s1.x, tk[4]);
            tk[5] = fmaf(cf, s1.y, tk[5]);
            tk[6] = fmaf(cf, s1.z, tk[6]);
            tk[7] = fmaf(cf, s1.w, tk[7]);
        }
        if (k == 0) {
            // -128 pixel shift folded: only the DC row has nonzero DCT row-sum.
#pragma unroll
            for (int m = 0; m < 8; ++m)
                tk[m] -= K0_SHIFT;
        }

        // ---- Stage-2 butterfly over m ----
        float u[4], v[4];
#pragma unroll
        for (int m = 0; m < 4; ++m) {
            u[m] = tk[m] + tk[7 - m];
            v[m] = tk[m] - tk[7 - m];
        }

#pragma unroll
        for (int l = 0; l < 8; ++l) {
            const bool evl = (l & 1) == 0;
            float s = 0.0f;
#pragma unroll
            for (int m = 0; m < 4; ++m)
                s = fmaf(DCT[l][m], evl ? u[m] : v[m], s);
            lds[wv][buf][l][lane] = s * rf * INVQ[k][l];
        }

#pragma unroll
        for (int it = 0; it < 2; ++it) {
            const int row = row0 + 4 * it;           // channel l within this k
            float4 vv = *reinterpret_cast<const float4*>(&lds[wv][buf][row][4 * chunk]);
            float* dst = out + obatch + (size_t)(k * 8 + row) * (HB * WB)
                             + (size_t)h * WB + wbase + 4 * chunk;
            *reinterpret_cast<float4*>(dst) = vv;
        }
    }
}

extern "C" void kernel_launch(void* const* d_in, const int* in_sizes, int n_in,
                              void* d_out, int out_size, void* d_ws, size_t ws_size,
                              hipStream_t stream) {
    const float* img = (const float*)d_in[0];
    const float* qf  = (const float*)d_in[1];
    float* out = (float*)d_out;

    const int grid = BATCH * (HB / 2);   // 1024 WGs: one per (batch, block-row pair)
    const int block = 256;

    jpeg_dct_q_kernel<<<grid, block, 0, stream>>>(img, qf, out);
}